// Round 1
// baseline (178.687 us; speedup 1.0000x reference)
//
#include <hip/hip_runtime.h>

// MHA forward: x[8,1024,768] fp32; Wq/Wk/Wv[12,768,64] fp32 -> out[8,1024,768] fp32
// Pipeline: cvt x->f16, cvt W->f16 transposed, QKV proj GEMM (f16 MFMA), flash attn (f16 MFMA).

#define Bq 8
#define Sq 1024
#define Dq 768
#define Hq 12
#define DHq 64

typedef _Float16 f16;
typedef f16 f16x8 __attribute__((ext_vector_type(8)));
typedef float f32x4 __attribute__((ext_vector_type(4)));

#define MFMA16(a, b, c) __builtin_amdgcn_mfma_f32_16x16x32_f16(a, b, c, 0, 0, 0)

// ---------- convert x (fp32 -> f16), 8 elems/thread ----------
__global__ __launch_bounds__(256) void cvt_x_kernel(const float* __restrict__ x,
                                                    f16* __restrict__ xh) {
  int i = blockIdx.x * 256 + threadIdx.x;  // 786432 threads
  const float4* src = reinterpret_cast<const float4*>(x) + i * 2;
  float4 a = src[0], b = src[1];
  f16x8 o;
  o[0] = (f16)a.x; o[1] = (f16)a.y; o[2] = (f16)a.z; o[3] = (f16)a.w;
  o[4] = (f16)b.x; o[5] = (f16)b.y; o[6] = (f16)b.z; o[7] = (f16)b.w;
  *reinterpret_cast<f16x8*>(xh + i * 8) = o;
}

// ---------- convert W -> WT f16, layout [w(0=q,1=k,2=v)][h][e(64)][k(768)] ----------
__global__ __launch_bounds__(256) void cvt_w_kernel(const float* __restrict__ Wq,
                                                    const float* __restrict__ Wk,
                                                    const float* __restrict__ Wv,
                                                    f16* __restrict__ WT) {
  int o = blockIdx.x * 256 + threadIdx.x;  // 1769472 total
  int k = o % Dq;
  int t2 = o / Dq;          // (w*12+h)*64 + e
  int e = t2 & 63;
  int hh = (t2 >> 6) % Hq;
  int w = (t2 >> 6) / Hq;
  const float* W = (w == 0) ? Wq : (w == 1) ? Wk : Wv;
  WT[o] = (f16)(W[(hh * Dq + k) * DHq + e]);
}

// ---------- QKV projection: block = (m-tile 64 rows, head). tile 64x192, K=768 ----------
__global__ __launch_bounds__(256) void proj_kernel(const f16* __restrict__ xh,
                                                   const f16* __restrict__ WT,
                                                   f16* __restrict__ Q,
                                                   f16* __restrict__ K,
                                                   f16* __restrict__ V) {
  __shared__ __align__(16) f16 lds_a[64][40];    // 64 rows x 32 k, pad->40
  __shared__ __align__(16) f16 lds_b[192][40];   // 192 n x 32 k, pad->40
  const int mt = blockIdx.x;  // 0..127
  const int h = blockIdx.y;   // 0..11
  const int row0 = mt * 64;
  const int t = threadIdx.x;
  const int wv = t >> 6;
  const int lane = t & 63;

  f32x4 acc[12] = {};
  const f16* xsrc = xh + (size_t)row0 * Dq;
  const f16* wsrc = WT + (size_t)h * DHq * Dq;  // + w*12*64*768 + e*768 later

  for (int k0 = 0; k0 < Dq; k0 += 32) {
    {  // stage A: 64x32, 16B/thread
      int r = t >> 2, p = t & 3;
      uint4 d = *reinterpret_cast<const uint4*>(xsrc + r * Dq + k0 + p * 8);
      *reinterpret_cast<uint4*>(&lds_a[r][p * 8]) = d;
    }
#pragma unroll
    for (int i = 0; i < 3; i++) {  // stage B: 192x32, 3x16B/thread
      int c = t + 256 * i;
      int n = c >> 2, p = c & 3;
      int w = n >> 6, e = n & 63;
      uint4 d = *reinterpret_cast<const uint4*>(wsrc + ((size_t)w * Hq * DHq + e) * Dq + k0 + p * 8);
      *reinterpret_cast<uint4*>(&lds_b[n][p * 8]) = d;
    }
    __syncthreads();
    f16x8 af = *reinterpret_cast<const f16x8*>(&lds_a[wv * 16 + (lane & 15)][(lane >> 4) * 8]);
#pragma unroll
    for (int nt = 0; nt < 12; nt++) {
      f16x8 bf = *reinterpret_cast<const f16x8*>(&lds_b[nt * 16 + (lane & 15)][(lane >> 4) * 8]);
      acc[nt] = MFMA16(af, bf, acc[nt]);
    }
    __syncthreads();
  }

  // write out: wave wv owns rows [wv*16, wv*16+16); C layout row=(lane>>4)*4+r, col=lane&15
  const int b = row0 >> 10;
  const int sbase = row0 + wv * 16 + ((lane >> 4) << 2);  // global s (row0 includes b*1024)
  const int col = lane & 15;
#pragma unroll
  for (int nt = 0; nt < 12; nt++) {
    int w = nt >> 2;
    int e = ((nt & 3) << 4) + col;
    f16* dst = (w == 0 ? Q : w == 1 ? K : V);
    size_t base = ((size_t)(b * Hq + h) * Sq) * DHq;
#pragma unroll
    for (int r = 0; r < 4; r++) {
      int s = (sbase & 1023) + r;
      dst[base + (size_t)s * DHq + e] = (f16)acc[nt][r];
    }
  }
}

// ---------- flash attention: block = (b,h,q-tile 64). 4 waves x 16 q-rows ----------
__global__ __launch_bounds__(256) void attn_kernel(const f16* __restrict__ Q,
                                                   const f16* __restrict__ K,
                                                   const f16* __restrict__ V,
                                                   float* __restrict__ out) {
  __shared__ __align__(16) f16 k_lds[64][72];      // [kv][dh] pad->72
  __shared__ __align__(16) f16 vt_lds[64][72];     // [dh][kv] pad->72
  __shared__ __align__(16) f16 p_lds[4][16][72];   // per-wave [q][kv]

  const int blk = blockIdx.x;  // 1536
  const int mt = blk & 15;
  const int bh = blk >> 4;  // 0..95
  const int t = threadIdx.x;
  const int wv = t >> 6;
  const int lane = t & 63;

  const f16* Qb = Q + (size_t)bh * Sq * DHq;
  const f16* Kb = K + (size_t)bh * Sq * DHq;
  const f16* Vb = V + (size_t)bh * Sq * DHq;

  const int q0 = mt * 64;
  const int qrow = q0 + wv * 16 + (lane & 15);
  f16x8 qf[2];
  qf[0] = *reinterpret_cast<const f16x8*>(Qb + (size_t)qrow * DHq + (lane >> 4) * 8);
  qf[1] = *reinterpret_cast<const f16x8*>(Qb + (size_t)qrow * DHq + 32 + (lane >> 4) * 8);

  f32x4 o_acc[4] = {};
  float m_r[4], l_r[4];
#pragma unroll
  for (int r = 0; r < 4; r++) { m_r[r] = -__builtin_inff(); l_r[r] = 0.f; }
  const int q_stat = q0 + wv * 16 + ((lane >> 4) << 2);  // + r = this lane's global q row

  for (int kt = 0; kt <= mt; kt++) {
    const int kv0 = kt * 64;
    {  // stage K (linear) and V (transposed)
      int r = t >> 2, p = t & 3;
      uint4 d0 = *reinterpret_cast<const uint4*>(Kb + (size_t)(kv0 + r) * DHq + p * 16);
      uint4 d1 = *reinterpret_cast<const uint4*>(Kb + (size_t)(kv0 + r) * DHq + p * 16 + 8);
      *reinterpret_cast<uint4*>(&k_lds[r][p * 16]) = d0;
      *reinterpret_cast<uint4*>(&k_lds[r][p * 16 + 8]) = d1;
      union UU { uint4 v; f16 hh[8]; } u0, u1;
      u0.v = *reinterpret_cast<const uint4*>(Vb + (size_t)(kv0 + r) * DHq + p * 16);
      u1.v = *reinterpret_cast<const uint4*>(Vb + (size_t)(kv0 + r) * DHq + p * 16 + 8);
#pragma unroll
      for (int j = 0; j < 8; j++) vt_lds[p * 16 + j][r] = u0.hh[j];
#pragma unroll
      for (int j = 0; j < 8; j++) vt_lds[p * 16 + 8 + j][r] = u1.hh[j];
    }
    __syncthreads();

    // S = Q K^T (scaled later). 4 kv n-tiles x 2 k-steps
    f32x4 sf[4] = {};
#pragma unroll
    for (int nt = 0; nt < 4; nt++) {
#pragma unroll
      for (int ks = 0; ks < 2; ks++) {
        f16x8 kf = *reinterpret_cast<const f16x8*>(
            &k_lds[nt * 16 + (lane & 15)][ks * 32 + (lane >> 4) * 8]);
        sf[nt] = MFMA16(qf[ks], kf, sf[nt]);
      }
    }

    // scale + causal mask
#pragma unroll
    for (int nt = 0; nt < 4; nt++) {
      int kvg = kv0 + nt * 16 + (lane & 15);
#pragma unroll
      for (int r = 0; r < 4; r++) {
        float sv = sf[nt][r] * 0.125f;
        if (kvg > q_stat + r) sv = -__builtin_inff();
        sf[nt][r] = sv;
      }
    }

    // online softmax per row r (rows owned by 16-lane groups)
    float pv[4][4];
#pragma unroll
    for (int r = 0; r < 4; r++) {
      float rowmax = fmaxf(fmaxf(sf[0][r], sf[1][r]), fmaxf(sf[2][r], sf[3][r]));
#pragma unroll
      for (int mμ = 1; mμ < 16; mμ <<= 1) rowmax = fmaxf(rowmax, __shfl_xor(rowmax, mμ, 64));
      float mnew = fmaxf(m_r[r], rowmax);
      float corr = __expf(m_r[r] - mnew);
      float rs = 0.f;
#pragma unroll
      for (int nt = 0; nt < 4; nt++) {
        float pe = __expf(sf[nt][r] - mnew);
        pv[nt][r] = pe;
        rs += pe;
      }
#pragma unroll
      for (int mμ = 1; mμ < 16; mμ <<= 1) rs += __shfl_xor(rs, mμ, 64);
      l_r[r] = l_r[r] * corr + rs;
      m_r[r] = mnew;
#pragma unroll
      for (int nt = 0; nt < 4; nt++) o_acc[nt][r] *= corr;
    }
    // write P (f16) into per-wave LDS
#pragma unroll
    for (int nt = 0; nt < 4; nt++)
#pragma unroll
      for (int r = 0; r < 4; r++)
        p_lds[wv][((lane >> 4) << 2) + r][nt * 16 + (lane & 15)] = (f16)pv[nt][r];
    __syncthreads();

    // O += P V : A=P[16q x 64kv], B=V[64kv x 64dh] via vt_lds
#pragma unroll
    for (int ks = 0; ks < 2; ks++) {
      f16x8 pf = *reinterpret_cast<const f16x8*>(
          &p_lds[wv][lane & 15][ks * 32 + (lane >> 4) * 8]);
#pragma unroll
      for (int nt = 0; nt < 4; nt++) {
        f16x8 vf = *reinterpret_cast<const f16x8*>(
            &vt_lds[nt * 16 + (lane & 15)][ks * 32 + (lane >> 4) * 8]);
        o_acc[nt] = MFMA16(pf, vf, o_acc[nt]);
      }
    }
    __syncthreads();
  }

  // epilogue: out[b][s][h*64+dh] = o/l
  const int b = bh / Hq, h = bh % Hq;
  float rl[4];
#pragma unroll
  for (int r = 0; r < 4; r++) rl[r] = 1.f / l_r[r];
#pragma unroll
  for (int nt = 0; nt < 4; nt++) {
    int dh = nt * 16 + (lane & 15);
#pragma unroll
    for (int r = 0; r < 4; r++) {
      int s = q_stat + r;
      out[((size_t)(b * Sq + s)) * (Hq * DHq) + h * DHq + dh] = o_acc[nt][r] * rl[r];
    }
  }
}

extern "C" void kernel_launch(void* const* d_in, const int* in_sizes, int n_in,
                              void* d_out, int out_size, void* d_ws, size_t ws_size,
                              hipStream_t stream) {
  const float* x = (const float*)d_in[0];
  const float* Wq = (const float*)d_in[1];
  const float* Wk = (const float*)d_in[2];
  const float* Wv = (const float*)d_in[3];
  float* out = (float*)d_out;

  const size_t off_xb = 0;                    // 8192*768*2      = 12,582,912
  const size_t off_wt = 12582912;             // 2304*768*2      =  3,538,944
  const size_t off_q = 16121856;              // 96*1024*64*2    = 12,582,912
  const size_t off_k = 28704768;
  const size_t off_v = 41287680;
  const size_t need = 53870592;
  if (ws_size < need) return;  // insufficient workspace -> visible failure

  char* ws = (char*)d_ws;
  f16* xh = (f16*)(ws + off_xb);
  f16* WT = (f16*)(ws + off_wt);
  f16* Qd = (f16*)(ws + off_q);
  f16* Kd = (f16*)(ws + off_k);
  f16* Vd = (f16*)(ws + off_v);

  cvt_x_kernel<<<3072, 256, 0, stream>>>(x, xh);
  cvt_w_kernel<<<6912, 256, 0, stream>>>(Wq, Wk, Wv, WT);
  proj_kernel<<<dim3(128, 12), 256, 0, stream>>>(xh, WT, Qd, Kd, Vd);
  attn_kernel<<<1536, 256, 0, stream>>>(Qd, Kd, Vd, out);
}

// Round 2
// 138.695 us; speedup vs baseline: 1.2883x; 1.2883x over previous
//
#include <hip/hip_runtime.h>

// MHA forward: x[8,1024,768] fp32; Wq/Wk/Wv[12,768,64] fp32 -> out[8,1024,768] fp32
// Pipeline: cvt x->f16, cvt W->f16 transposed, QKV proj GEMM (f16 MFMA, writes V transposed),
// flash attn (f16 MFMA, paired q-tiles for causal load balance).

#define Bq 8
#define Sq 1024
#define Dq 768
#define Hq 12
#define DHq 64

typedef _Float16 f16;
typedef f16 f16x8 __attribute__((ext_vector_type(8)));
typedef float f32x4 __attribute__((ext_vector_type(4)));

#define MFMA16(a, b, c) __builtin_amdgcn_mfma_f32_16x16x32_f16(a, b, c, 0, 0, 0)

// 0.125 (1/sqrt(64)) * log2(e): folded into Q so attn works in exp2 domain
#define QSCL 0.1803368801111244f

// ---------- convert x (fp32 -> f16), 8 elems/thread ----------
__global__ __launch_bounds__(256) void cvt_x_kernel(const float* __restrict__ x,
                                                    f16* __restrict__ xh) {
  int i = blockIdx.x * 256 + threadIdx.x;  // 98304 threads
  const float4* src = reinterpret_cast<const float4*>(x) + i * 2;
  float4 a = src[0], b = src[1];
  f16x8 o;
  o[0] = (f16)a.x; o[1] = (f16)a.y; o[2] = (f16)a.z; o[3] = (f16)a.w;
  o[4] = (f16)b.x; o[5] = (f16)b.y; o[6] = (f16)b.z; o[7] = (f16)b.w;
  *reinterpret_cast<f16x8*>(xh + i * 8) = o;
}

// ---------- convert W -> WT f16, layout [w(0=q,1=k,2=v)][h][e(64)][k(768)] ----------
__global__ __launch_bounds__(256) void cvt_w_kernel(const float* __restrict__ Wq,
                                                    const float* __restrict__ Wk,
                                                    const float* __restrict__ Wv,
                                                    f16* __restrict__ WT) {
  int o = blockIdx.x * 256 + threadIdx.x;  // 1769472 total
  int k = o % Dq;
  int t2 = o / Dq;          // (w*12+h)*64 + e
  int e = t2 & 63;
  int hh = (t2 >> 6) % Hq;
  int w = (t2 >> 6) / Hq;
  const float* W = (w == 0) ? Wq : (w == 1) ? Wk : Wv;
  WT[o] = (f16)(W[(hh * Dq + k) * DHq + e]);
}

// ---------- QKV projection: block = (m-tile 64 rows, head). tile 64x192, BK=64 ----------
// Writes Q (pre-scaled by QSCL), K in [bh][s][dh]; V transposed to [bh][dh][s].
__global__ __launch_bounds__(256) void proj_kernel(const f16* __restrict__ xh,
                                                   const f16* __restrict__ WT,
                                                   f16* __restrict__ Q,
                                                   f16* __restrict__ K,
                                                   f16* __restrict__ Vt) {
  __shared__ __align__(16) f16 lds_a[64][72];    // 64 rows x 64 k, pad->72
  __shared__ __align__(16) f16 lds_b[192][72];   // 192 n x 64 k, pad->72
  const int mt = blockIdx.x;  // 0..127
  const int h = blockIdx.y;   // 0..11
  const int row0 = mt * 64;
  const int t = threadIdx.x;
  const int wv = t >> 6;
  const int lane = t & 63;

  f32x4 acc[12] = {};
  const f16* xsrc = xh + (size_t)row0 * Dq;
  const f16* wsrc = WT + (size_t)h * DHq * Dq;

  for (int k0 = 0; k0 < Dq; k0 += 64) {
#pragma unroll
    for (int i = 0; i < 2; i++) {  // stage A: 64x64, 512 chunks of 16B
      int c = t + 256 * i;
      int r = c >> 3, p = c & 7;
      *reinterpret_cast<uint4*>(&lds_a[r][p * 8]) =
          *reinterpret_cast<const uint4*>(xsrc + (size_t)r * Dq + k0 + p * 8);
    }
#pragma unroll
    for (int i = 0; i < 6; i++) {  // stage B: 192x64, 1536 chunks of 16B
      int c = t + 256 * i;
      int n = c >> 3, p = c & 7;
      int w = n >> 6, e = n & 63;
      *reinterpret_cast<uint4*>(&lds_b[n][p * 8]) =
          *reinterpret_cast<const uint4*>(wsrc + ((size_t)w * Hq * DHq + e) * Dq + k0 + p * 8);
    }
    __syncthreads();
    f16x8 af[2];
    af[0] = *reinterpret_cast<const f16x8*>(&lds_a[wv * 16 + (lane & 15)][(lane >> 4) * 8]);
    af[1] = *reinterpret_cast<const f16x8*>(&lds_a[wv * 16 + (lane & 15)][32 + (lane >> 4) * 8]);
#pragma unroll
    for (int nt = 0; nt < 12; nt++) {
#pragma unroll
      for (int ks = 0; ks < 2; ks++) {
        f16x8 bf = *reinterpret_cast<const f16x8*>(
            &lds_b[nt * 16 + (lane & 15)][ks * 32 + (lane >> 4) * 8]);
        acc[nt] = MFMA16(af[ks], bf, acc[nt]);
      }
    }
    __syncthreads();
  }

  const int b = row0 >> 10;
  const int s0 = row0 & 1023;
  const int sbase = wv * 16 + ((lane >> 4) << 2);  // local s base for this lane
  const int col = lane & 15;
  const size_t base_sd = ((size_t)(b * Hq + h) * Sq) * DHq;

  // Q (scaled) and K: [bh][s][dh]
#pragma unroll
  for (int nt = 0; nt < 8; nt++) {
    int w = nt >> 2;
    int e = ((nt & 3) << 4) + col;
    f16* dst = (w == 0 ? Q : K);
    float scl = (w == 0) ? QSCL : 1.0f;
#pragma unroll
    for (int r = 0; r < 4; r++) {
      dst[base_sd + (size_t)(s0 + sbase + r) * DHq + e] = (f16)(acc[nt][r] * scl);
    }
  }

  // V: transpose through LDS (reuse lds_b rows 0..63) then coalesced write to [bh][dh][s]
#pragma unroll
  for (int nt = 8; nt < 12; nt++) {
    int e = ((nt & 3) << 4) + col;
#pragma unroll
    for (int r = 0; r < 4; r++) {
      lds_b[e][sbase + r] = (f16)acc[nt][r];
    }
  }
  __syncthreads();
#pragma unroll
  for (int i = 0; i < 2; i++) {  // 64 rows x 128B = 512 chunks of 16B
    int c = t + 256 * i;
    int e = c >> 3, p = c & 7;
    *reinterpret_cast<uint4*>(Vt + base_sd + (size_t)e * Sq + s0 + p * 8) =
        *reinterpret_cast<const uint4*>(&lds_b[e][p * 8]);
  }
}

// ---------- flash attention: block = (bh, pair-index). 4 waves x 16 q-rows ----------
// Each block processes two q-tiles (pr and 15-pr) -> uniform 17 KV iterations/block.
__global__ __launch_bounds__(256) void attn_kernel(const f16* __restrict__ Q,
                                                   const f16* __restrict__ K,
                                                   const f16* __restrict__ Vt,
                                                   float* __restrict__ out) {
  __shared__ __align__(16) f16 k_lds[64][72];      // [kv][dh] pad->72
  __shared__ __align__(16) f16 vt_lds[64][72];     // [dh][kv] pad->72
  __shared__ __align__(16) f16 p_lds[4][16][72];   // per-wave [q][kv]

  const int blk = blockIdx.x;  // 768
  const int pr = blk & 7;
  const int bh = blk >> 3;  // 0..95
  const int t = threadIdx.x;
  const int wv = t >> 6;
  const int lane = t & 63;

  const f16* Qb = Q + (size_t)bh * Sq * DHq;
  const f16* Kb = K + (size_t)bh * Sq * DHq;
  const f16* Vtb = Vt + (size_t)bh * DHq * Sq;
  const int b = bh / Hq, h = bh % Hq;

  for (int ph = 0; ph < 2; ph++) {
    const int mt = ph ? (15 - pr) : pr;
    const int q0 = mt * 64;
    const int qrow = q0 + wv * 16 + (lane & 15);
    f16x8 qf[2];
    qf[0] = *reinterpret_cast<const f16x8*>(Qb + (size_t)qrow * DHq + (lane >> 4) * 8);
    qf[1] = *reinterpret_cast<const f16x8*>(Qb + (size_t)qrow * DHq + 32 + (lane >> 4) * 8);

    f32x4 o_acc[4] = {};
    float m_r[4], l_r[4];
#pragma unroll
    for (int r = 0; r < 4; r++) { m_r[r] = -__builtin_inff(); l_r[r] = 0.f; }
    const int q_stat = q0 + wv * 16 + ((lane >> 4) << 2);

    for (int kt = 0; kt <= mt; kt++) {
      const int kv0 = kt * 64;
#pragma unroll
      for (int i = 0; i < 2; i++) {  // stage K [kv][dh] and Vt [dh][kv], 16B chunks
        int c = t + 256 * i;
        int r = c >> 3, p = c & 7;
        *reinterpret_cast<uint4*>(&k_lds[r][p * 8]) =
            *reinterpret_cast<const uint4*>(Kb + (size_t)(kv0 + r) * DHq + p * 8);
        *reinterpret_cast<uint4*>(&vt_lds[r][p * 8]) =
            *reinterpret_cast<const uint4*>(Vtb + (size_t)r * Sq + kv0 + p * 8);
      }
      __syncthreads();

      // S~ = (Q*QSCL) K^T  (already in exp2 domain)
      f32x4 sf[4] = {};
#pragma unroll
      for (int nt = 0; nt < 4; nt++) {
#pragma unroll
        for (int ks = 0; ks < 2; ks++) {
          f16x8 kf = *reinterpret_cast<const f16x8*>(
              &k_lds[nt * 16 + (lane & 15)][ks * 32 + (lane >> 4) * 8]);
          sf[nt] = MFMA16(qf[ks], kf, sf[nt]);
        }
      }

      // causal mask: only the diagonal tile needs it
      if (kt == mt) {
#pragma unroll
        for (int nt = 0; nt < 4; nt++) {
          int kvg = kv0 + nt * 16 + (lane & 15);
#pragma unroll
          for (int r = 0; r < 4; r++) {
            if (kvg > q_stat + r) sf[nt][r] = -__builtin_inff();
          }
        }
      }

      // online softmax per row r (rows owned by 16-lane groups), exp2 domain
      float pv[4][4];
#pragma unroll
      for (int r = 0; r < 4; r++) {
        float rowmax = fmaxf(fmaxf(sf[0][r], sf[1][r]), fmaxf(sf[2][r], sf[3][r]));
#pragma unroll
        for (int mm = 1; mm < 16; mm <<= 1) rowmax = fmaxf(rowmax, __shfl_xor(rowmax, mm, 64));
        float mnew = fmaxf(m_r[r], rowmax);
        float corr = exp2f(m_r[r] - mnew);
        float rs = 0.f;
#pragma unroll
        for (int nt = 0; nt < 4; nt++) {
          float pe = exp2f(sf[nt][r] - mnew);
          pv[nt][r] = pe;
          rs += pe;
        }
#pragma unroll
        for (int mm = 1; mm < 16; mm <<= 1) rs += __shfl_xor(rs, mm, 64);
        l_r[r] = l_r[r] * corr + rs;
        m_r[r] = mnew;
#pragma unroll
        for (int nt = 0; nt < 4; nt++) o_acc[nt][r] *= corr;
      }
      // write P (f16) into per-wave LDS (no barrier needed: same-wave producer/consumer)
#pragma unroll
      for (int nt = 0; nt < 4; nt++)
#pragma unroll
        for (int r = 0; r < 4; r++)
          p_lds[wv][((lane >> 4) << 2) + r][nt * 16 + (lane & 15)] = (f16)pv[nt][r];

      // O += P V : A=P[16q x 64kv], B=V[64kv x 64dh] via vt_lds
#pragma unroll
      for (int ks = 0; ks < 2; ks++) {
        f16x8 pf = *reinterpret_cast<const f16x8*>(
            &p_lds[wv][lane & 15][ks * 32 + (lane >> 4) * 8]);
#pragma unroll
        for (int nt = 0; nt < 4; nt++) {
          f16x8 vf = *reinterpret_cast<const f16x8*>(
              &vt_lds[nt * 16 + (lane & 15)][ks * 32 + (lane >> 4) * 8]);
          o_acc[nt] = MFMA16(pf, vf, o_acc[nt]);
        }
      }
      __syncthreads();
    }

    // epilogue: out[b][s][h*64+dh] = o/l
    float rl[4];
#pragma unroll
    for (int r = 0; r < 4; r++) rl[r] = 1.f / l_r[r];
#pragma unroll
    for (int nt = 0; nt < 4; nt++) {
      int dh = nt * 16 + (lane & 15);
#pragma unroll
      for (int r = 0; r < 4; r++) {
        int s = q_stat + r;
        out[((size_t)(b * Sq + s)) * (Hq * DHq) + h * DHq + dh] = o_acc[nt][r] * rl[r];
      }
    }
  }
}

extern "C" void kernel_launch(void* const* d_in, const int* in_sizes, int n_in,
                              void* d_out, int out_size, void* d_ws, size_t ws_size,
                              hipStream_t stream) {
  const float* x = (const float*)d_in[0];
  const float* Wq = (const float*)d_in[1];
  const float* Wk = (const float*)d_in[2];
  const float* Wv = (const float*)d_in[3];
  float* out = (float*)d_out;

  const size_t off_xb = 0;                    // 8192*768*2      = 12,582,912
  const size_t off_wt = 12582912;             // 2304*768*2      =  3,538,944
  const size_t off_q = 16121856;              // 96*1024*64*2    = 12,582,912
  const size_t off_k = 28704768;
  const size_t off_v = 41287680;
  const size_t need = 53870592;
  if (ws_size < need) return;  // insufficient workspace -> visible failure

  char* ws = (char*)d_ws;
  f16* xh = (f16*)(ws + off_xb);
  f16* WT = (f16*)(ws + off_wt);
  f16* Qd = (f16*)(ws + off_q);
  f16* Kd = (f16*)(ws + off_k);
  f16* Vtd = (f16*)(ws + off_v);

  cvt_x_kernel<<<3072, 256, 0, stream>>>(x, xh);
  cvt_w_kernel<<<6912, 256, 0, stream>>>(Wq, Wk, Wv, WT);
  proj_kernel<<<dim3(128, 12), 256, 0, stream>>>(xh, WT, Qd, Kd, Vtd);
  attn_kernel<<<768, 256, 0, stream>>>(Qd, Kd, Vtd, out);
}

// Round 4
// 109.120 us; speedup vs baseline: 1.6375x; 1.2710x over previous
//
#include <hip/hip_runtime.h>

// MHA forward: x[8,1024,768] fp32; Wq/Wk/Wv[12,768,64] fp32 -> out[8,1024,768] fp32
// cvt x->f16, cvt W->f16T, QKV proj (f16 MFMA, M=128 tile, writes V transposed),
// flash attn: swapped-operand MFMA (S^T = K Q^T, O^T = V^T P^T) -> in-lane softmax,
// in-register P redistribution (16 shfl + dest-side select), double-buffered K/V.

#define Bq 8
#define Sq 1024
#define Dq 768
#define Hq 12
#define DHq 64

typedef _Float16 f16;
typedef f16 f16x8 __attribute__((ext_vector_type(8)));
typedef float f32x4 __attribute__((ext_vector_type(4)));

#define MFMA16(a, b, c) __builtin_amdgcn_mfma_f32_16x16x32_f16(a, b, c, 0, 0, 0)

// 0.125 (1/sqrt(64)) * log2(e): folded into Q so attn works in exp2 domain
#define QSCL 0.1803368801111244f

#if __has_builtin(__builtin_amdgcn_exp2f)
#define EXP2(x) __builtin_amdgcn_exp2f(x)
#else
#define EXP2(x) exp2f(x)
#endif

// ---------- convert x (fp32 -> f16), 8 elems/thread ----------
__global__ __launch_bounds__(256) void cvt_x_kernel(const float* __restrict__ x,
                                                    f16* __restrict__ xh) {
  int i = blockIdx.x * 256 + threadIdx.x;
  const float4* src = reinterpret_cast<const float4*>(x) + i * 2;
  float4 a = src[0], b = src[1];
  f16x8 o;
  o[0] = (f16)a.x; o[1] = (f16)a.y; o[2] = (f16)a.z; o[3] = (f16)a.w;
  o[4] = (f16)b.x; o[5] = (f16)b.y; o[6] = (f16)b.z; o[7] = (f16)b.w;
  *reinterpret_cast<f16x8*>(xh + i * 8) = o;
}

// ---------- convert W -> WT f16, layout [w(0=q,1=k,2=v)][h][e(64)][k(768)] ----------
__global__ __launch_bounds__(256) void cvt_w_kernel(const float* __restrict__ Wq,
                                                    const float* __restrict__ Wk,
                                                    const float* __restrict__ Wv,
                                                    f16* __restrict__ WT) {
  int o = blockIdx.x * 256 + threadIdx.x;
  int k = o % Dq;
  int t2 = o / Dq;
  int e = t2 & 63;
  int hh = (t2 >> 6) % Hq;
  int w = (t2 >> 6) / Hq;
  const float* W = (w == 0) ? Wq : (w == 1) ? Wk : Wv;
  WT[o] = (f16)(W[(hh * Dq + k) * DHq + e]);
}

// ---------- QKV projection: block = (128-row m-tile, head). tile 128x192, BK=64 ----------
__global__ __launch_bounds__(256) void proj_kernel(const f16* __restrict__ xh,
                                                   const f16* __restrict__ WT,
                                                   f16* __restrict__ Q,
                                                   f16* __restrict__ K,
                                                   f16* __restrict__ Vt) {
  __shared__ __align__(16) f16 lds_a[128][72];
  __shared__ __align__(16) f16 lds_b[192][72];
  const int mt = blockIdx.x;  // 0..63
  const int h = blockIdx.y;   // 0..11
  const int row0 = mt * 128;
  const int t = threadIdx.x;
  const int wv = t >> 6;
  const int lane = t & 63;
  const int g = lane >> 4;
  const int ql = lane & 15;

  f32x4 acc0[12] = {};
  f32x4 acc1[12] = {};
  const f16* xsrc = xh + (size_t)row0 * Dq;
  const f16* wsrc = WT + (size_t)h * DHq * Dq;

  for (int k0 = 0; k0 < Dq; k0 += 64) {
#pragma unroll
    for (int i = 0; i < 4; i++) {  // stage A: 128x64
      int c = t + 256 * i;
      int r = c >> 3, p = (c & 7) * 8;
      *reinterpret_cast<uint4*>(&lds_a[r][p]) =
          *reinterpret_cast<const uint4*>(xsrc + (size_t)r * Dq + k0 + p);
    }
#pragma unroll
    for (int i = 0; i < 6; i++) {  // stage B: 192x64
      int c = t + 256 * i;
      int n = c >> 3, p = (c & 7) * 8;
      int w = n >> 6, e = n & 63;
      *reinterpret_cast<uint4*>(&lds_b[n][p]) =
          *reinterpret_cast<const uint4*>(wsrc + ((size_t)w * Hq * DHq + e) * Dq + k0 + p);
    }
    __syncthreads();
#pragma unroll
    for (int ks = 0; ks < 2; ks++) {
      f16x8 a0 = *reinterpret_cast<const f16x8*>(&lds_a[wv * 32 + ql][ks * 32 + g * 8]);
      f16x8 a1 = *reinterpret_cast<const f16x8*>(&lds_a[wv * 32 + 16 + ql][ks * 32 + g * 8]);
#pragma unroll
      for (int nt = 0; nt < 12; nt++) {
        f16x8 bf = *reinterpret_cast<const f16x8*>(&lds_b[nt * 16 + ql][ks * 32 + g * 8]);
        acc0[nt] = MFMA16(a0, bf, acc0[nt]);
        acc1[nt] = MFMA16(a1, bf, acc1[nt]);
      }
    }
    __syncthreads();
  }

  const int b = row0 >> 10;
  const int s0 = row0 & 1023;
  const size_t base_sd = ((size_t)(b * Hq + h) * Sq) * DHq;

  // Q (pre-scaled) and K: [bh][s][dh]
#pragma unroll
  for (int sm = 0; sm < 2; sm++) {
    const int sl = wv * 32 + sm * 16 + g * 4;
#pragma unroll
    for (int nt = 0; nt < 8; nt++) {
      int w = nt >> 2;
      int e = ((nt & 3) << 4) + ql;
      f16* dst = (w == 0 ? Q : K);
      float scl = (w == 0) ? QSCL : 1.0f;
      const f32x4& a = sm ? acc1[nt] : acc0[nt];
#pragma unroll
      for (int r = 0; r < 4; r++)
        dst[base_sd + (size_t)(s0 + sl + r) * DHq + e] = (f16)(a[r] * scl);
    }
  }

  // V: transpose via lds_b flat [64 e][136] then coalesced write to [bh][dh][s]
  f16* vbuf = &lds_b[0][0];
#pragma unroll
  for (int sm = 0; sm < 2; sm++) {
    const int sl = wv * 32 + sm * 16 + g * 4;
#pragma unroll
    for (int nt = 8; nt < 12; nt++) {
      int e = ((nt - 8) << 4) + ql;
      const f32x4& a = sm ? acc1[nt] : acc0[nt];
#pragma unroll
      for (int r = 0; r < 4; r++) vbuf[e * 136 + sl + r] = (f16)a[r];
    }
  }
  __syncthreads();
#pragma unroll
  for (int i = 0; i < 4; i++) {  // 64 e-rows x 128 s = 1024 chunks of 16B
    int c = t + 256 * i;
    int e = c >> 4, p = (c & 15) * 8;
    *reinterpret_cast<uint4*>(Vt + base_sd + (size_t)e * Sq + s0 + p) =
        *reinterpret_cast<const uint4*>(vbuf + e * 136 + p);
  }
}

// ---------- flash attention: swapped-operand, dbuf K/V, 1 barrier/iter ----------
__global__ __launch_bounds__(256) void attn_kernel(const f16* __restrict__ Q,
                                                   const f16* __restrict__ K,
                                                   const f16* __restrict__ Vt,
                                                   float* __restrict__ out) {
  __shared__ __align__(16) f16 k_lds[2][64][72];   // [buf][kv][dh]
  __shared__ __align__(16) f16 vt_lds[2][64][72];  // [buf][dh][kv]

  const int blk = blockIdx.x;  // 768
  const int pr = blk & 7;
  const int bh = blk >> 3;
  const int t = threadIdx.x;
  const int wv = t >> 6;
  const int lane = t & 63;
  const int g = lane >> 4;
  const int ql = lane & 15;

  const f16* Qb = Q + (size_t)bh * Sq * DHq;
  const f16* Kb = K + (size_t)bh * Sq * DHq;
  const f16* Vtb = Vt + (size_t)bh * DHq * Sq;
  const int b = bh / Hq, h = bh % Hq;

  const int r0 = t >> 3;          // staging row 0..31 (and +32)
  const int p0 = (t & 7) * 8;     // staging col offset (f16 elems)

  for (int ph = 0; ph < 2; ph++) {
    const int mt = ph ? (15 - pr) : pr;
    const int q0 = mt * 64;
    const int qg = q0 + wv * 16 + ql;  // this lane's q row (global within bh)
    f16x8 qf0 = *reinterpret_cast<const f16x8*>(Qb + (size_t)qg * DHq + g * 8);
    f16x8 qf1 = *reinterpret_cast<const f16x8*>(Qb + (size_t)qg * DHq + 32 + g * 8);

    f32x4 o_acc[4] = {};
    float m_r = -__builtin_inff(), l_r = 0.f;

    uint4 kreg0, kreg1, vreg0, vreg1;
    // stage kt=0 directly
    kreg0 = *reinterpret_cast<const uint4*>(Kb + (size_t)r0 * DHq + p0);
    kreg1 = *reinterpret_cast<const uint4*>(Kb + (size_t)(32 + r0) * DHq + p0);
    vreg0 = *reinterpret_cast<const uint4*>(Vtb + (size_t)r0 * Sq + p0);
    vreg1 = *reinterpret_cast<const uint4*>(Vtb + (size_t)(32 + r0) * Sq + p0);
    *reinterpret_cast<uint4*>(&k_lds[0][r0][p0]) = kreg0;
    *reinterpret_cast<uint4*>(&k_lds[0][32 + r0][p0]) = kreg1;
    *reinterpret_cast<uint4*>(&vt_lds[0][r0][p0]) = vreg0;
    *reinterpret_cast<uint4*>(&vt_lds[0][32 + r0][p0]) = vreg1;
    if (mt >= 1) {  // prefetch kt=1
      kreg0 = *reinterpret_cast<const uint4*>(Kb + (size_t)(64 + r0) * DHq + p0);
      kreg1 = *reinterpret_cast<const uint4*>(Kb + (size_t)(96 + r0) * DHq + p0);
      vreg0 = *reinterpret_cast<const uint4*>(Vtb + (size_t)r0 * Sq + 64 + p0);
      vreg1 = *reinterpret_cast<const uint4*>(Vtb + (size_t)(32 + r0) * Sq + 64 + p0);
    }
    __syncthreads();

    int cur = 0;
    for (int kt = 0; kt <= mt; kt++) {
      // S^T = K Q^T : lane holds q=qg, kv_local = nt*16 + g*4 + r
      f32x4 sf[4] = {};
#pragma unroll
      for (int nt = 0; nt < 4; nt++) {
        f16x8 kf0 = *reinterpret_cast<const f16x8*>(&k_lds[cur][nt * 16 + ql][g * 8]);
        f16x8 kf1 = *reinterpret_cast<const f16x8*>(&k_lds[cur][nt * 16 + ql][32 + g * 8]);
        sf[nt] = MFMA16(kf0, qf0, sf[nt]);
        sf[nt] = MFMA16(kf1, qf1, sf[nt]);
      }

      if (kt == mt) {  // causal mask on the diagonal tile
#pragma unroll
        for (int nt = 0; nt < 4; nt++)
#pragma unroll
          for (int r = 0; r < 4; r++)
            if (nt * 16 + g * 4 + r > wv * 16 + ql) sf[nt][r] = -__builtin_inff();
      }

      // in-lane softmax (exp2 domain): lane owns 16 of 64 kv values of one q-row
      float rowmax = sf[0][0];
#pragma unroll
      for (int nt = 0; nt < 4; nt++)
#pragma unroll
        for (int r = 0; r < 4; r++) rowmax = fmaxf(rowmax, sf[nt][r]);
      rowmax = fmaxf(rowmax, __shfl_xor(rowmax, 16, 64));
      rowmax = fmaxf(rowmax, __shfl_xor(rowmax, 32, 64));
      float mnew = fmaxf(m_r, rowmax);
      float corr = EXP2(m_r - mnew);
      float p[4][4];
      float rs = 0.f;
#pragma unroll
      for (int nt = 0; nt < 4; nt++)
#pragma unroll
        for (int r = 0; r < 4; r++) {
          float pe = EXP2(sf[nt][r] - mnew);
          p[nt][r] = pe;
          rs += pe;
        }
      rs += __shfl_xor(rs, 16, 64);
      rs += __shfl_xor(rs, 32, 64);
      l_r = l_r * corr + rs;
      m_r = mnew;
#pragma unroll
      for (int nt = 0; nt < 4; nt++) {
        o_acc[nt][0] *= corr; o_acc[nt][1] *= corr;
        o_acc[nt][2] *= corr; o_acc[nt][3] *= corr;
      }

      // pack P to f16 pairs: pk[nt][p2] = P[qg][kv = nt*16 + g*4 + 2*p2 + {0,1}]
      uint32_t pk[4][2];
#pragma unroll
      for (int nt = 0; nt < 4; nt++) {
        union { f16 hh[2]; uint32_t u; } z0, z1;
        z0.hh[0] = (f16)p[nt][0]; z0.hh[1] = (f16)p[nt][1];
        z1.hh[0] = (f16)p[nt][2]; z1.hh[1] = (f16)p[nt][3];
        pk[nt][0] = z0.u; pk[nt][1] = z1.u;
      }
      // Redistribute to P^T B-fragments. Dest lane (g,ql) word i of pf[ks] needs
      // pk[2ks + (g>>1)][i&1] from source lane g_src = 2*(g&1) + (i>>1), same ql.
      // __shfl evaluates the var at the SOURCE lane, so shuffle BOTH nt candidates
      // and select with the destination's own (g>>1).
      const int srcA = ((g & 1) * 2) * 16 + ql;
      const int srcB = srcA + 16;
      const bool selhi = (g >> 1) != 0;
      f16x8 pf[2];
#pragma unroll
      for (int ks = 0; ks < 2; ks++) {
        uint32_t aA0 = (uint32_t)__shfl((int)pk[2 * ks][0], srcA, 64);
        uint32_t aA1 = (uint32_t)__shfl((int)pk[2 * ks][1], srcA, 64);
        uint32_t aB0 = (uint32_t)__shfl((int)pk[2 * ks][0], srcB, 64);
        uint32_t aB1 = (uint32_t)__shfl((int)pk[2 * ks][1], srcB, 64);
        uint32_t bA0 = (uint32_t)__shfl((int)pk[2 * ks + 1][0], srcA, 64);
        uint32_t bA1 = (uint32_t)__shfl((int)pk[2 * ks + 1][1], srcA, 64);
        uint32_t bB0 = (uint32_t)__shfl((int)pk[2 * ks + 1][0], srcB, 64);
        uint32_t bB1 = (uint32_t)__shfl((int)pk[2 * ks + 1][1], srcB, 64);
        union { uint32_t w[4]; f16x8 v; } z;
        z.w[0] = selhi ? bA0 : aA0;
        z.w[1] = selhi ? bA1 : aA1;
        z.w[2] = selhi ? bB0 : aB0;
        z.w[3] = selhi ? bB1 : aB1;
        pf[ks] = z.v;
      }

      // O^T += V^T P^T : o_acc[nt] has dh = nt*16 + g*4 + r, q = qg
#pragma unroll
      for (int nt = 0; nt < 4; nt++) {
        f16x8 vf0 = *reinterpret_cast<const f16x8*>(&vt_lds[cur][nt * 16 + ql][g * 8]);
        f16x8 vf1 = *reinterpret_cast<const f16x8*>(&vt_lds[cur][nt * 16 + ql][32 + g * 8]);
        o_acc[nt] = MFMA16(vf0, pf[0], o_acc[nt]);
        o_acc[nt] = MFMA16(vf1, pf[1], o_acc[nt]);
      }

      // write next tile from regs; issue loads for kt+2
      if (kt < mt) {
        *reinterpret_cast<uint4*>(&k_lds[cur ^ 1][r0][p0]) = kreg0;
        *reinterpret_cast<uint4*>(&k_lds[cur ^ 1][32 + r0][p0]) = kreg1;
        *reinterpret_cast<uint4*>(&vt_lds[cur ^ 1][r0][p0]) = vreg0;
        *reinterpret_cast<uint4*>(&vt_lds[cur ^ 1][32 + r0][p0]) = vreg1;
        if (kt + 2 <= mt) {
          const int kv0 = (kt + 2) * 64;
          kreg0 = *reinterpret_cast<const uint4*>(Kb + (size_t)(kv0 + r0) * DHq + p0);
          kreg1 = *reinterpret_cast<const uint4*>(Kb + (size_t)(kv0 + 32 + r0) * DHq + p0);
          vreg0 = *reinterpret_cast<const uint4*>(Vtb + (size_t)r0 * Sq + kv0 + p0);
          vreg1 = *reinterpret_cast<const uint4*>(Vtb + (size_t)(32 + r0) * Sq + kv0 + p0);
        }
      }
      __syncthreads();
      cur ^= 1;
    }

    // epilogue: out[b][q][h*64 + dh], 4 consecutive dh per lane -> float4
    float rl = 1.0f / l_r;
    float* op = out + ((size_t)(b * Sq + qg)) * (Hq * DHq) + h * DHq;
#pragma unroll
    for (int nt = 0; nt < 4; nt++) {
      float4 st = { o_acc[nt][0] * rl, o_acc[nt][1] * rl,
                    o_acc[nt][2] * rl, o_acc[nt][3] * rl };
      *reinterpret_cast<float4*>(op + nt * 16 + g * 4) = st;
    }
  }
}

extern "C" void kernel_launch(void* const* d_in, const int* in_sizes, int n_in,
                              void* d_out, int out_size, void* d_ws, size_t ws_size,
                              hipStream_t stream) {
  const float* x = (const float*)d_in[0];
  const float* Wq = (const float*)d_in[1];
  const float* Wk = (const float*)d_in[2];
  const float* Wv = (const float*)d_in[3];
  float* out = (float*)d_out;

  const size_t off_xb = 0;                    // 8192*768*2      = 12,582,912
  const size_t off_wt = 12582912;             // 2304*768*2      =  3,538,944
  const size_t off_q = 16121856;              // 96*1024*64*2    = 12,582,912
  const size_t off_k = 28704768;
  const size_t off_v = 41287680;
  const size_t need = 53870592;
  if (ws_size < need) return;

  char* ws = (char*)d_ws;
  f16* xh = (f16*)(ws + off_xb);
  f16* WT = (f16*)(ws + off_wt);
  f16* Qd = (f16*)(ws + off_q);
  f16* Kd = (f16*)(ws + off_k);
  f16* Vtd = (f16*)(ws + off_v);

  cvt_x_kernel<<<3072, 256, 0, stream>>>(x, xh);
  cvt_w_kernel<<<6912, 256, 0, stream>>>(Wq, Wk, Wv, WT);
  proj_kernel<<<dim3(64, 12), 256, 0, stream>>>(xh, WT, Qd, Kd, Vtd);
  attn_kernel<<<768, 256, 0, stream>>>(Qd, Kd, Vtd, out);
}